// Round 16
// baseline (1064.098 us; speedup 1.0000x reference)
//
#include <hip/hip_runtime.h>
#include <hip/hip_fp16.h>

#define N_NODES 50000
#define N_EDGES 800000
#define HD 128
#define NLAYERS 5
#define EINC 16
#define NG 512
#define BN_EPS 1e-5f
#define CHUNK 32

typedef _Float16 half8 __attribute__((ext_vector_type(8)));
typedef _Float16 half2v __attribute__((ext_vector_type(2)));
typedef float f32x4 __attribute__((ext_vector_type(4)));
typedef float f32x2 __attribute__((ext_vector_type(2)));

// ---------------- embedding: h (fp16) = emb[x[n]] ----------------
__global__ __launch_bounds__(256) void k_embed(const int* __restrict__ x,
                                               const float* __restrict__ emb,
                                               _Float16* __restrict__ h) {
  int i = blockIdx.x * 256 + threadIdx.x;       // 8-ch groups
  if (i < N_NODES * 16) {
    int n = i >> 4, cv = i & 15;
    const float* src = &emb[(size_t)x[n] * HD + cv * 8];
    float4 a0 = *(const float4*)&src[0];
    float4 a1 = *(const float4*)&src[4];
    half8 p;
    p[0] = (_Float16)a0.x; p[1] = (_Float16)a0.y; p[2] = (_Float16)a0.z; p[3] = (_Float16)a0.w;
    p[4] = (_Float16)a1.x; p[5] = (_Float16)a1.y; p[6] = (_Float16)a1.z; p[7] = (_Float16)a1.w;
    *(half8*)&h[(size_t)n * HD + cv * 8] = p;
  }
}

// ---------------- CSR build ----------------
__global__ __launch_bounds__(256) void k_hist(const int* __restrict__ ei,
                                              int* __restrict__ deg) {
  int e = blockIdx.x * 256 + threadIdx.x;
  if (e < N_EDGES) atomicAdd(&deg[ei[N_EDGES + e]], 1);
}

__global__ __launch_bounds__(256) void k_scan1(const int* __restrict__ deg,
                                               int* __restrict__ incl,
                                               int* __restrict__ bsum) {
  __shared__ int s[256];
  int i = blockIdx.x * 256 + threadIdx.x;
  int v = (i < N_NODES) ? deg[i] : 0;
  s[threadIdx.x] = v;
  __syncthreads();
  for (int d = 1; d < 256; d <<= 1) {
    int t = (threadIdx.x >= d) ? s[threadIdx.x - d] : 0;
    __syncthreads();
    s[threadIdx.x] += t;
    __syncthreads();
  }
  if (i < N_NODES) incl[i] = s[threadIdx.x];
  if (threadIdx.x == 255) bsum[blockIdx.x] = s[255];
}

__global__ void k_scan2(int* __restrict__ bsum, int nb) {
  __shared__ int s[256];
  int v = (threadIdx.x < nb) ? bsum[threadIdx.x] : 0;
  s[threadIdx.x] = v;
  __syncthreads();
  for (int d = 1; d < 256; d <<= 1) {
    int t = (threadIdx.x >= d) ? s[threadIdx.x - d] : 0;
    __syncthreads();
    s[threadIdx.x] += t;
    __syncthreads();
  }
  if (threadIdx.x < nb) bsum[threadIdx.x] = s[threadIdx.x];
}

__global__ __launch_bounds__(256) void k_scan3(const int* __restrict__ deg,
                                               const int* __restrict__ incl,
                                               const int* __restrict__ bsum,
                                               int* __restrict__ offs,
                                               int* __restrict__ cursor) {
  int i = blockIdx.x * 256 + threadIdx.x;
  if (i < N_NODES) {
    int base = (blockIdx.x > 0) ? bsum[blockIdx.x - 1] : 0;
    int start = base + incl[i] - deg[i];
    offs[i] = start;
    cursor[i] = start;
    if (i == N_NODES - 1) offs[N_NODES] = N_EDGES;
  }
}

// scatter one packed int2 {src, eid} per edge (single 8B store)
__global__ __launch_bounds__(256) void k_scatter(const int* __restrict__ ei,
                                                 int* __restrict__ cursor,
                                                 int2* __restrict__ edata) {
  int e = blockIdx.x * 256 + threadIdx.x;
  if (e < N_EDGES) {
    int dst = ei[N_EDGES + e];
    int pos = atomicAdd(&cursor[dst], 1);
    edata[pos] = make_int2(ei[e], e);
  }
}

// permute ea into CSR order as fp16 rows (16 halves = 32B); emit sequential srcs.
// rows [N_EDGES, N_EDGES+64) zeroed (MFMA tail slack).
__global__ __launch_bounds__(256) void k_permea(const int2* __restrict__ edata,
                                                const float* __restrict__ ea,
                                                int* __restrict__ srcs,
                                                _Float16* __restrict__ ea_h) {
  int p = blockIdx.x * 256 + threadIdx.x;
  if (p < N_EDGES) {
    int2 d = edata[p];
    srcs[p] = d.x;
    const float* r = &ea[(size_t)d.y * EINC];
    half8 o0, o1;
#pragma unroll
    for (int k = 0; k < 8; ++k) { o0[k] = (_Float16)r[k]; o1[k] = (_Float16)r[8 + k]; }
    *(half8*)&ea_h[(size_t)p * EINC] = o0;
    *(half8*)&ea_h[(size_t)p * EINC + 8] = o1;
  } else if (p < N_EDGES + 64) {
    half8 zz;
#pragma unroll
    for (int k = 0; k < 8; ++k) zz[k] = (_Float16)0.f;
    *(half8*)&ea_h[(size_t)p * EINC] = zz;
    *(half8*)&ea_h[(size_t)p * EINC + 8] = zz;
  }
}

// ---------------- merged weight convert (once per launch) ----------------
// [0, 163840): w1t[l][n][k] = W1[l][k][n]   (n<256,k<128)
// [163840, 327680): w2t[l][n][k] = W2[l][k][n]  (n<128,k<256)
// [327680, 337920): eWt[l][n][k] = eW[l][k][n]  (n<128,k<16)
__global__ __launch_bounds__(256) void k_cvtw(const float* __restrict__ W1,
                                              const float* __restrict__ W2,
                                              const float* __restrict__ eW,
                                              _Float16* __restrict__ w1t,
                                              _Float16* __restrict__ w2t,
                                              _Float16* __restrict__ eWt) {
  int i = blockIdx.x * 256 + threadIdx.x;
  if (i < 163840) {
    int l = i >> 15, r = i & 32767;
    int n = r >> 7, k = r & 127;
    w1t[i] = (_Float16)W1[(size_t)l * 32768 + k * 256 + n];
  } else if (i < 327680) {
    int j = i - 163840;
    int l = j >> 15, r = j & 32767;
    int n = r >> 8, k = r & 255;
    w2t[j] = (_Float16)W2[(size_t)l * 32768 + k * 128 + n];
  } else if (i < 337920) {
    int j = i - 327680;
    int l = j >> 11, r = j & 2047;
    int n = r >> 4, k = r & 15;
    eWt[j] = (_Float16)eW[(size_t)l * 2048 + k * 128 + n];
  }
}

// -------- fused per-node aggregation: MFMA(16x16x32) edge-MLP + gather/relu/acc --------
// Per block: 2 nodes, 4 waves. Chunks of 32 CSR edges:
//  phase A: E[32 x 128] as 2 edge-tiles x 8 ch-tiles of 16x16; wave w owns ch [w*32,w*32+32)
//           -> 4 MFMAs/wave (K=32, upper half zero-padded); verified 16x16x32 layouts.
//  phase B: per-edge gather h[src], bn+relu, add e, accumulate (parity-split per node)
__global__ __launch_bounds__(256) void k_aggr(const int* __restrict__ offs,
                                              const int* __restrict__ srcs,
                                              const _Float16* __restrict__ ea_h,  // [N_EDGES+64][16] CSR order
                                              const _Float16* __restrict__ eWt,   // [128][16] layer slice
                                              const float* __restrict__ eb,       // [128]
                                              const float* __restrict__ epsA, int layer,
                                              const _Float16* __restrict__ hraw,
                                              const float* __restrict__ gsum2,    // prev layer raw stats
                                              const float* __restrict__ gsq2,
                                              const float* __restrict__ bng,
                                              const float* __restrict__ bnb,
                                              int fuse_bn,
                                              _Float16* __restrict__ z) {
  __shared__ _Float16 sE[CHUNK * HD];   // 8 KB
  __shared__ int sSrc[CHUNK];
  __shared__ float sP[2 * HD];
  const int tid = threadIdx.x;
  const int w = tid >> 6;
  const int lane = tid & 63;
  const int nodeIdx = w >> 1, sub = w & 1;
  const int n0 = blockIdx.x * 2;
  const int n = n0 + nodeIdx;
  const int c0 = lane * 2;

  // --- MFMA constants (verified 16x16x32 layouts; A/B: row|col=lane&15, k=(lane>>4)*8+j) ---
  const int chw = w * 32;
  const int l15 = lane & 15;
  const int lg = lane >> 4;             // k-group; groups 2,3 cover k>=16 -> zero pad
  half8 hzero8;
#pragma unroll
  for (int q = 0; q < 8; ++q) hzero8[q] = (_Float16)0.f;
  half8 bfrag[2];
  f32x4 cinit[2];
#pragma unroll
  for (int ct = 0; ct < 2; ++ct) {
    int col = chw + ct * 16 + l15;
    bfrag[ct] = (lg < 2) ? *(const half8*)&eWt[(size_t)col * EINC + lg * 8] : hzero8;
    float bv = eb[col];
    f32x4 ci; ci[0] = bv; ci[1] = bv; ci[2] = bv; ci[3] = bv;
    cinit[ct] = ci;
  }

  // --- consume constants (per thread: node, channel pair) ---
  half2v hz; hz[0] = (_Float16)0.f; hz[1] = (_Float16)0.f;
  half2v sch = hz, shh = hz;
  if (fuse_bn) {
    const float invN = 1.0f / (float)N_NODES;
    float m0 = gsum2[c0] * invN, m1 = gsum2[c0 + 1] * invN;
    float v0 = fmaxf(gsq2[c0] * invN - m0 * m0, 0.0f);
    float v1 = fmaxf(gsq2[c0 + 1] * invN - m1 * m1, 0.0f);
    float s0 = bng[c0] * rsqrtf(v0 + BN_EPS);
    float s1 = bng[c0 + 1] * rsqrtf(v1 + BN_EPS);
    sch[0] = (_Float16)s0; sch[1] = (_Float16)s1;
    shh[0] = (_Float16)(bnb[c0] - m0 * s0);
    shh[1] = (_Float16)(bnb[c0 + 1] - m1 * s1);
  }
  const float epsv = 1.0f + epsA[layer];

  const int jA = offs[n0];
  const int jEnd = offs[n0 + 2];
  const int myLo = offs[n];
  const int myHi = offs[n + 1];

  f32x2 acc = {0.f, 0.f};
  for (int base = jA; base < jEnd; base += CHUNK) {
    int cnt = jEnd - base; if (cnt > CHUNK) cnt = CHUNK;
    __syncthreads();   // protect sE/sSrc from previous chunk's consumers
    if (tid < CHUNK) sSrc[tid] = (base + tid < jEnd) ? srcs[base + tid] : 0;
    // A-frags straight from global (coalesced; tail covered by zero-pad rows)
    half8 afrag[2];
#pragma unroll
    for (int et = 0; et < 2; ++et) {
      size_t row = (size_t)base + et * 16 + l15;
      afrag[et] = (lg < 2) ? *(const half8*)&ea_h[row * EINC + lg * 8] : hzero8;
    }
#pragma unroll
    for (int et = 0; et < 2; ++et)
#pragma unroll
      for (int ct = 0; ct < 2; ++ct) {
        f32x4 D = __builtin_amdgcn_mfma_f32_16x16x32_f16(afrag[et], bfrag[ct], cinit[ct], 0, 0, 0);
#pragma unroll
        for (int r = 0; r < 4; ++r)
          sE[(et * 16 + lg * 4 + r) * HD + chw + ct * 16 + l15] = (_Float16)D[r];
      }
    __syncthreads();   // E ready
    // consume: this wave's node, every other edge (parity = sub)
    int lo = myLo > base ? myLo : base;
    int hi = myHi < base + cnt ? myHi : base + cnt;
    for (int j = lo + sub; j < hi; j += 2) {
      int jl = j - base;
      half2v e2 = *(const half2v*)&sE[jl * HD + c0];
      int src = sSrc[jl];
      half2v hv = *(const half2v*)&hraw[(size_t)src * HD + c0];
      if (fuse_bn) hv = __builtin_elementwise_max(__builtin_elementwise_fma(hv, sch, shh), hz);
      half2v m = __builtin_elementwise_max(hv + e2, hz);
      acc[0] += (float)m[0];
      acc[1] += (float)m[1];
    }
  }

  __syncthreads();
  if (sub) {
    sP[nodeIdx * HD + c0] = acc[0];
    sP[nodeIdx * HD + c0 + 1] = acc[1];
  }
  __syncthreads();
  if (!sub) {
    half2v hv = *(const half2v*)&hraw[(size_t)n * HD + c0];
    if (fuse_bn) hv = __builtin_elementwise_max(__builtin_elementwise_fma(hv, sch, shh), hz);
    acc[0] += epsv * (float)hv[0] + sP[nodeIdx * HD + c0];
    acc[1] += epsv * (float)hv[1] + sP[nodeIdx * HD + c0 + 1];
    half2v oz; oz[0] = (_Float16)acc[0]; oz[1] = (_Float16)acc[1];
    *(half2v*)&z[(size_t)n * HD + c0] = oz;
  }
}

// ---------- GEMM1 (MFMA fp16): y1h = fp16(z @ W1 + b1) ; col stats ----------
__global__ __launch_bounds__(256) void k_gemm1m(const _Float16* __restrict__ z,
                                                const _Float16* __restrict__ w1t, // [256][128]
                                                const float* __restrict__ bias,   // [256]
                                                _Float16* __restrict__ y1h,
                                                float* __restrict__ gsum,
                                                float* __restrict__ gsq) {
  __shared__ char smemRaw[20480];
  _Float16* sA = (_Float16*)smemRaw;
  _Float16* sBT = (_Float16*)(smemRaw + 10240);
  float* sOut = (float*)smemRaw;
  __shared__ float ssum[128], ssq[128];
  const int tid = threadIdx.x;
  const int lane = tid & 63;
  const int wid = tid >> 6;
  const int wm = wid >> 1, wn = wid & 1;
  const int m0 = blockIdx.x * 128;
  const int n0 = blockIdx.y * 128;

  if (tid < 128) { ssum[tid] = 0.f; ssq[tid] = 0.f; }

  f32x4 acc[4][4];
  const f32x4 zz = {0.f, 0.f, 0.f, 0.f};
#pragma unroll
  for (int a = 0; a < 4; ++a)
#pragma unroll
    for (int b = 0; b < 4; ++b) acc[a][b] = zz;

  const int srow = tid >> 1;
  const int skh = (tid & 1) * 16;

  for (int k0 = 0; k0 < 128; k0 += 32) {
    {
      int nn = m0 + srow;
      half8 p0, p1;
      if (nn < N_NODES) {
        p0 = *(const half8*)&z[(size_t)nn * 128 + k0 + skh];
        p1 = *(const half8*)&z[(size_t)nn * 128 + k0 + skh + 8];
      } else {
#pragma unroll
        for (int j = 0; j < 8; ++j) { p0[j] = (_Float16)0.f; p1[j] = (_Float16)0.f; }
      }
      *(half8*)&sA[srow * 40 + skh] = p0;
      *(half8*)&sA[srow * 40 + skh + 8] = p1;
    }
    {
      half8 u0 = *(const half8*)&w1t[(size_t)(n0 + srow) * 128 + k0 + skh];
      half8 u1 = *(const half8*)&w1t[(size_t)(n0 + srow) * 128 + k0 + skh + 8];
      *(half8*)&sBT[srow * 40 + skh] = u0;
      *(half8*)&sBT[srow * 40 + skh + 8] = u1;
    }
    __syncthreads();
    half8 af[4], bf[4];
#pragma unroll
    for (int t = 0; t < 4; ++t) {
      af[t] = *(const half8*)&sA[(wm * 64 + t * 16 + (lane & 15)) * 40 + (lane >> 4) * 8];
      bf[t] = *(const half8*)&sBT[(wn * 64 + t * 16 + (lane & 15)) * 40 + (lane >> 4) * 8];
    }
#pragma unroll
    for (int tm = 0; tm < 4; ++tm)
#pragma unroll
      for (int tn = 0; tn < 4; ++tn)
        acc[tm][tn] = __builtin_amdgcn_mfma_f32_16x16x32_f16(af[tm], bf[tn], acc[tm][tn], 0, 0, 0);
    __syncthreads();
  }

  float bsv[4];
#pragma unroll
  for (int tn = 0; tn < 4; ++tn) bsv[tn] = bias[n0 + wn * 64 + tn * 16 + (lane & 15)];
  {
    float sacc[4] = {0.f, 0.f, 0.f, 0.f}, qacc[4] = {0.f, 0.f, 0.f, 0.f};
#pragma unroll
    for (int tm = 0; tm < 4; ++tm) {
      int nbase = m0 + wm * 64 + tm * 16 + (lane >> 4) * 4;
#pragma unroll
      for (int r = 0; r < 4; ++r) {
        if (nbase + r < N_NODES) {
#pragma unroll
          for (int tn = 0; tn < 4; ++tn) {
            float v = acc[tm][tn][r] + bsv[tn];
            sacc[tn] += v; qacc[tn] += v * v;
          }
        }
      }
    }
#pragma unroll
    for (int tn = 0; tn < 4; ++tn) {
      int c = wn * 64 + tn * 16 + (lane & 15);
      atomicAdd(&ssum[c], sacc[tn]);
      atomicAdd(&ssq[c], qacc[tn]);
    }
  }

  for (int c = 0; c < 4; ++c) {
    __syncthreads();
    if (wm == (c >> 1)) {
#pragma unroll
      for (int t2 = 0; t2 < 2; ++t2) {
        int tm = (c & 1) * 2 + t2;
#pragma unroll
        for (int tn = 0; tn < 4; ++tn)
#pragma unroll
          for (int r = 0; r < 4; ++r)
            sOut[(t2 * 16 + (lane >> 4) * 4 + r) * 132 + wn * 64 + tn * 16 + (lane & 15)] =
                acc[tm][tn][r] + bsv[tn];
      }
    }
    __syncthreads();
    int row = tid >> 3;
    int cb = (tid & 7) * 16;
    int gn = m0 + c * 32 + row;
    if (gn < N_NODES) {
      const float* rp = &sOut[row * 132 + cb];
      half8 o0, o1;
#pragma unroll
      for (int q = 0; q < 8; ++q) o0[q] = (_Float16)rp[q];
#pragma unroll
      for (int q = 0; q < 8; ++q) o1[q] = (_Float16)rp[8 + q];
      *(half8*)&y1h[(size_t)gn * 256 + n0 + cb] = o0;
      *(half8*)&y1h[(size_t)gn * 256 + n0 + cb + 8] = o1;
    }
  }
  __syncthreads();
  if (tid < 128) {
    unsafeAtomicAdd(&gsum[n0 + tid], ssum[tid]);
    unsafeAtomicAdd(&gsq[n0 + tid], ssq[tid]);
  }
}

// ---------- GEMM2 (MFMA fp16): hraw(fp16) = relu(bn1(y1h)) @ W2 + b2 ; col stats ----------
__global__ __launch_bounds__(256) void k_gemm2m(const _Float16* __restrict__ y1h,
                                                const float* __restrict__ gsum1,
                                                const float* __restrict__ gsq1,
                                                const float* __restrict__ g1r,
                                                const float* __restrict__ be1r,
                                                const _Float16* __restrict__ w2t, // [128][256]
                                                const float* __restrict__ bias,   // [128]
                                                _Float16* __restrict__ y2,
                                                float* __restrict__ gsum,
                                                float* __restrict__ gsq) {
  __shared__ char smemRaw[16896];
  _Float16* sA = (_Float16*)smemRaw;
  _Float16* sBT = (_Float16*)(smemRaw + 5120);
  float* sOut = (float*)smemRaw;
  __shared__ float ssc[256], ssh[256];
  __shared__ float ssum[128], ssq[128];
  const int tid = threadIdx.x;
  const int lane = tid & 63;
  const int wid = tid >> 6;
  const int wm = wid >> 1, wn = wid & 1;
  const int m0 = blockIdx.x * 64;

  {
    const float invN = 1.0f / (float)N_NODES;
    float m = gsum1[tid] * invN;
    float v = fmaxf(gsq1[tid] * invN - m * m, 0.0f);
    float s = g1r[tid] * rsqrtf(v + BN_EPS);
    ssc[tid] = s;
    ssh[tid] = be1r[tid] - m * s;
  }
  if (tid < 128) { ssum[tid] = 0.f; ssq[tid] = 0.f; }
  __syncthreads();

  f32x4 acc[2][4];
  const f32x4 zz = {0.f, 0.f, 0.f, 0.f};
#pragma unroll
  for (int a = 0; a < 2; ++a)
#pragma unroll
    for (int b = 0; b < 4; ++b) acc[a][b] = zz;

  const int arow = tid >> 2;
  const int akq = (tid & 3) * 8;
  const int brow = tid >> 1;
  const int bkh = (tid & 1) * 16;

  for (int k0 = 0; k0 < 256; k0 += 32) {
    {
      int nn = m0 + arow;
      half8 p;
      if (nn < N_NODES) {
        half8 yv = *(const half8*)&y1h[(size_t)nn * 256 + k0 + akq];
#pragma unroll
        for (int j = 0; j < 8; ++j) {
          float v = fmaxf((float)yv[j] * ssc[k0 + akq + j] + ssh[k0 + akq + j], 0.f);
          p[j] = (_Float16)v;
        }
      } else {
#pragma unroll
        for (int j = 0; j < 8; ++j) p[j] = (_Float16)0.f;
      }
      *(half8*)&sA[arow * 40 + akq] = p;
    }
    {
      half8 u0 = *(const half8*)&w2t[(size_t)brow * 256 + k0 + bkh];
      half8 u1 = *(const half8*)&w2t[(size_t)brow * 256 + k0 + bkh + 8];
      *(half8*)&sBT[brow * 40 + bkh] = u0;
      *(half8*)&sBT[brow * 40 + bkh + 8] = u1;
    }
    __syncthreads();
    half8 af[2], bf[4];
#pragma unroll
    for (int t = 0; t < 2; ++t)
      af[t] = *(const half8*)&sA[(wm * 32 + t * 16 + (lane & 15)) * 40 + (lane >> 4) * 8];
#pragma unroll
    for (int t = 0; t < 4; ++t)
      bf[t] = *(const half8*)&sBT[(wn * 64 + t * 16 + (lane & 15)) * 40 + (lane >> 4) * 8];
#pragma unroll
    for (int tm = 0; tm < 2; ++tm)
#pragma unroll
      for (int tn = 0; tn < 4; ++tn)
        acc[tm][tn] = __builtin_amdgcn_mfma_f32_16x16x32_f16(af[tm], bf[tn], acc[tm][tn], 0, 0, 0);
    __syncthreads();
  }

  float bsv[4];
#pragma unroll
  for (int tn = 0; tn < 4; ++tn) bsv[tn] = bias[wn * 64 + tn * 16 + (lane & 15)];
  {
    float sacc[4] = {0.f, 0.f, 0.f, 0.f}, qacc[4] = {0.f, 0.f, 0.f, 0.f};
#pragma unroll
    for (int tm = 0; tm < 2; ++tm) {
      int nbase = m0 + wm * 32 + tm * 16 + (lane >> 4) * 4;
#pragma unroll
      for (int r = 0; r < 4; ++r) {
        if (nbase + r < N_NODES) {
#pragma unroll
          for (int tn = 0; tn < 4; ++tn) {
            float v = acc[tm][tn][r] + bsv[tn];
            sacc[tn] += v; qacc[tn] += v * v;
          }
        }
      }
    }
#pragma unroll
    for (int tn = 0; tn < 4; ++tn) {
      int c = wn * 64 + tn * 16 + (lane & 15);
      atomicAdd(&ssum[c], sacc[tn]);
      atomicAdd(&ssq[c], qacc[tn]);
    }
  }

  for (int c = 0; c < 2; ++c) {
    __syncthreads();
    if (wm == c) {
#pragma unroll
      for (int tm = 0; tm < 2; ++tm)
#pragma unroll
        for (int tn = 0; tn < 4; ++tn)
#pragma unroll
          for (int r = 0; r < 4; ++r)
            sOut[(tm * 16 + (lane >> 4) * 4 + r) * 132 + wn * 64 + tn * 16 + (lane & 15)] =
                acc[tm][tn][r] + bsv[tn];
    }
    __syncthreads();
    int row = tid >> 3;
    int cb = (tid & 7) * 16;
    int gn = m0 + c * 32 + row;
    if (gn < N_NODES) {
      const float* rp = &sOut[row * 132 + cb];
      half8 o0, o1;
#pragma unroll
      for (int q = 0; q < 8; ++q) o0[q] = (_Float16)rp[q];
#pragma unroll
      for (int q = 0; q < 8; ++q) o1[q] = (_Float16)rp[8 + q];
      *(half8*)&y2[(size_t)gn * 128 + cb] = o0;
      *(half8*)&y2[(size_t)gn * 128 + cb + 8] = o1;
    }
  }
  __syncthreads();
  if (tid < 128) {
    unsafeAtomicAdd(&gsum[tid], ssum[tid]);
    unsafeAtomicAdd(&gsq[tid], ssq[tid]);
  }
}

// ---------------- pooling with inlined final BN ----------------
__global__ void k_goff(const int* __restrict__ batch, int* __restrict__ goff) {
  int g = blockIdx.x * blockDim.x + threadIdx.x;
  if (g <= NG) {
    if (g == NG) { goff[g] = N_NODES; return; }
    int lo = 0, hi = N_NODES;
    while (lo < hi) { int mid = (lo + hi) >> 1; if (batch[mid] < g) lo = mid + 1; else hi = mid; }
    goff[g] = lo;
  }
}

__global__ __launch_bounds__(256) void k_poolseg(const _Float16* __restrict__ y2raw,
                                                 const float* __restrict__ gsum2,
                                                 const float* __restrict__ gsq2,
                                                 const float* __restrict__ bng,
                                                 const float* __restrict__ bnb,
                                                 const int* __restrict__ goff,
                                                 float* __restrict__ pooled) {
  __shared__ float sred[256];
  int g = blockIdx.x;
  int c = threadIdx.x & 127;
  int half = threadIdx.x >> 7;
  int n0 = goff[g], n1 = goff[g + 1];
  float s = 0.f;
  for (int n = n0 + half; n < n1; n += 2) s += (float)y2raw[(size_t)n * HD + c];
  sred[threadIdx.x] = s;
  __syncthreads();
  if (threadIdx.x < 128) {
    const float invN = 1.0f / (float)N_NODES;
    float m = gsum2[threadIdx.x] * invN;
    float v = fmaxf(gsq2[threadIdx.x] * invN - m * m, 0.0f);
    float scv = bng[threadIdx.x] * rsqrtf(v + BN_EPS);
    float shv = bnb[threadIdx.x] - m * scv;
    float tot = sred[threadIdx.x] + sred[threadIdx.x + 128];
    float cntf = fmaxf((float)(n1 - n0), 1.0f);
    pooled[g * HD + threadIdx.x] = scv * (tot / cntf) + shv;
  }
}

// ---------------- final GEMM ----------------
__global__ __launch_bounds__(128) void k_final(const float* __restrict__ pooled,
                                               const float* __restrict__ oW,
                                               const float* __restrict__ ob,
                                               float* __restrict__ out) {
  __shared__ float sP[HD];
  int g = blockIdx.x;
  int c = threadIdx.x;
  sP[c] = pooled[g * HD + c];
  __syncthreads();
  float acc = ob[c];
#pragma unroll 8
  for (int k = 0; k < HD; ++k) acc += sP[k] * oW[k * HD + c];
  out[g * HD + c] = acc;
}

extern "C" void kernel_launch(void* const* d_in, const int* in_sizes, int n_in,
                              void* d_out, int out_size, void* d_ws, size_t ws_size,
                              hipStream_t stream) {
  const int* x = (const int*)d_in[0];
  const int* ei = (const int*)d_in[1];
  const float* ea = (const float*)d_in[2];
  const int* batch = (const int*)d_in[3];
  const float* emb = (const float*)d_in[4];
  const float* eW = (const float*)d_in[5];
  const float* eb = (const float*)d_in[6];
  const float* epsA = (const float*)d_in[7];
  const float* W1 = (const float*)d_in[8];
  const float* b1 = (const float*)d_in[9];
  const float* g1 = (const float*)d_in[10];
  const float* be1 = (const float*)d_in[11];
  const float* W2 = (const float*)d_in[12];
  const float* b2 = (const float*)d_in[13];
  const float* bng = (const float*)d_in[14];
  const float* bnb = (const float*)d_in[15];
  const float* oW = (const float*)d_in[16];
  const float* ob = (const float*)d_in[17];
  float* out = (float*)d_out;

  // ----- workspace layout: ints first, then floats -----
  int* ip = (int*)d_ws;
  int* deg = ip;                              // 50,000
  int* incl = deg + 50000;                    // 50,000
  int* offs = incl + 50000;                   // 50,001
  int* cursor = offs + 50001;                 // 50,000
  int2* edata = (int2*)(cursor + 50000 + 1);  // 800,000 int2 (8B aligned)
  int* srcs = (int*)(edata + 800000);         // 800,000
  int* bsum = srcs + 800000;                  // 200
  int* goff = bsum + 200;                     // 513
  float* fp = (float*)(ip + 2600716);
  _Float16* h = (_Float16*)fp;                       // 6.4M halves -> fp[0 .. 3,200,000)
  _Float16* zbuf = (_Float16*)(fp + 3200000);        // 6.4M halves -> fp[3.2M .. 6.4M)
  _Float16* y1h = (_Float16*)(fp + 6400000);         // 12.8M halves -> fp[6.4M .. 12.8M)
  _Float16* ea_h = (_Float16*)(fp + 12800000);       // 800,064*16 halves = 6,400,512 f32 slots
  float* statsA = fp + 19200512;              // 5*768 (AFTER ea_h's true extent — R13/R15 overlap bug fixed)
  float* pooled = statsA + 3840;              // 65,536
  _Float16* w1t = (_Float16*)(pooled + 65536);       // 163,840 halves
  _Float16* w2t = w1t + 163840;                      // 163,840 halves
  _Float16* eWt = w2t + 163840;                      // 10,240 halves

  const int edge_blocks = (N_EDGES + 255) / 256;
  const int node_blocks = (N_NODES + 255) / 256;

  k_embed<<<(N_NODES * 16 + 255) / 256, 256, 0, stream>>>(x, emb, h);

  // CSR build + permuted fp16 ea + weight conversion + stats arena zero (once per launch)
  hipMemsetAsync(deg, 0, 50000 * sizeof(int), stream);
  hipMemsetAsync(statsA, 0, 3840 * sizeof(float), stream);
  k_hist<<<edge_blocks, 256, 0, stream>>>(ei, deg);
  k_scan1<<<node_blocks, 256, 0, stream>>>(deg, incl, bsum);
  k_scan2<<<1, 256, 0, stream>>>(bsum, node_blocks);
  k_scan3<<<node_blocks, 256, 0, stream>>>(deg, incl, bsum, offs, cursor);
  k_scatter<<<edge_blocks, 256, 0, stream>>>(ei, cursor, edata);
  k_permea<<<(N_EDGES + 64 + 255) / 256, 256, 0, stream>>>(edata, ea, srcs, ea_h);
  k_goff<<<3, 256, 0, stream>>>(batch, goff);
  k_cvtw<<<(337920 + 255) / 256, 256, 0, stream>>>(W1, W2, eW, w1t, w2t, eWt);

  for (int l = 0; l < NLAYERS; ++l) {
    float* st = statsA + (size_t)l * 768;         // gsum1 | gsq1 (256+256)
    float* st2 = st + 512;                        // gsum2 | gsq2 (128+128)
    const float* pst2 = statsA + (size_t)(l - 1) * 768 + 512;
    k_aggr<<<N_NODES / 2, 256, 0, stream>>>(offs, srcs, ea_h,
                                            eWt + (size_t)l * 2048, eb + l * HD,
                                            epsA, l, h,
                                            (l > 0) ? pst2 : statsA, (l > 0) ? pst2 + 128 : statsA,
                                            bng + (l > 0 ? (l - 1) : 0) * HD,
                                            bnb + (l > 0 ? (l - 1) : 0) * HD,
                                            (l > 0) ? 1 : 0, zbuf);
    k_gemm1m<<<dim3(391, 2), 256, 0, stream>>>(zbuf, w1t + (size_t)l * 32768,
                                               b1 + l * 256, y1h, st, st + 256);
    k_gemm2m<<<782, 256, 0, stream>>>(y1h, st, st + 256, g1 + l * 256, be1 + l * 256,
                                      w2t + (size_t)l * 32768, b2 + l * HD, h,
                                      st2, st2 + 128);
  }

  {
    const float* lst2 = statsA + (size_t)(NLAYERS - 1) * 768 + 512;
    k_poolseg<<<NG, 256, 0, stream>>>(h, lst2, lst2 + 128,
                                      bng + (NLAYERS - 1) * HD, bnb + (NLAYERS - 1) * HD,
                                      goff, pooled);
  }
  k_final<<<NG, 128, 0, stream>>>(pooled, oW, ob, out);
}

// Round 17
// 968.271 us; speedup vs baseline: 1.0990x; 1.0990x over previous
//
#include <hip/hip_runtime.h>
#include <hip/hip_fp16.h>

#define N_NODES 50000
#define N_EDGES 800000
#define HD 128
#define NLAYERS 5
#define EINC 16
#define NG 512
#define BN_EPS 1e-5f

typedef _Float16 half8 __attribute__((ext_vector_type(8)));
typedef _Float16 half2v __attribute__((ext_vector_type(2)));
typedef float f32x4 __attribute__((ext_vector_type(4)));
typedef float f32x2 __attribute__((ext_vector_type(2)));

__device__ inline half2v h2bc(uint32_t u) { return __builtin_bit_cast(half2v, u); }

// ---------------- embedding: h (fp16) = emb[x[n]] ----------------
__global__ __launch_bounds__(256) void k_embed(const int* __restrict__ x,
                                               const float* __restrict__ emb,
                                               _Float16* __restrict__ h) {
  int i = blockIdx.x * 256 + threadIdx.x;       // 8-ch groups
  if (i < N_NODES * 16) {
    int n = i >> 4, cv = i & 15;
    const float* src = &emb[(size_t)x[n] * HD + cv * 8];
    float4 a0 = *(const float4*)&src[0];
    float4 a1 = *(const float4*)&src[4];
    half8 p;
    p[0] = (_Float16)a0.x; p[1] = (_Float16)a0.y; p[2] = (_Float16)a0.z; p[3] = (_Float16)a0.w;
    p[4] = (_Float16)a1.x; p[5] = (_Float16)a1.y; p[6] = (_Float16)a1.z; p[7] = (_Float16)a1.w;
    *(half8*)&h[(size_t)n * HD + cv * 8] = p;
  }
}

// ---------------- CSR build ----------------
__global__ __launch_bounds__(256) void k_hist(const int* __restrict__ ei,
                                              int* __restrict__ deg) {
  int e = blockIdx.x * 256 + threadIdx.x;
  if (e < N_EDGES) atomicAdd(&deg[ei[N_EDGES + e]], 1);
}

__global__ __launch_bounds__(256) void k_scan1(const int* __restrict__ deg,
                                               int* __restrict__ incl,
                                               int* __restrict__ bsum) {
  __shared__ int s[256];
  int i = blockIdx.x * 256 + threadIdx.x;
  int v = (i < N_NODES) ? deg[i] : 0;
  s[threadIdx.x] = v;
  __syncthreads();
  for (int d = 1; d < 256; d <<= 1) {
    int t = (threadIdx.x >= d) ? s[threadIdx.x - d] : 0;
    __syncthreads();
    s[threadIdx.x] += t;
    __syncthreads();
  }
  if (i < N_NODES) incl[i] = s[threadIdx.x];
  if (threadIdx.x == 255) bsum[blockIdx.x] = s[255];
}

__global__ void k_scan2(int* __restrict__ bsum, int nb) {
  __shared__ int s[256];
  int v = (threadIdx.x < nb) ? bsum[threadIdx.x] : 0;
  s[threadIdx.x] = v;
  __syncthreads();
  for (int d = 1; d < 256; d <<= 1) {
    int t = (threadIdx.x >= d) ? s[threadIdx.x - d] : 0;
    __syncthreads();
    s[threadIdx.x] += t;
    __syncthreads();
  }
  if (threadIdx.x < nb) bsum[threadIdx.x] = s[threadIdx.x];
}

__global__ __launch_bounds__(256) void k_scan3(const int* __restrict__ deg,
                                               const int* __restrict__ incl,
                                               const int* __restrict__ bsum,
                                               int* __restrict__ offs,
                                               int* __restrict__ cursor) {
  int i = blockIdx.x * 256 + threadIdx.x;
  if (i < N_NODES) {
    int base = (blockIdx.x > 0) ? bsum[blockIdx.x - 1] : 0;
    int start = base + incl[i] - deg[i];
    offs[i] = start;
    cursor[i] = start;
    if (i == N_NODES - 1) offs[N_NODES] = N_EDGES;
  }
}

// scatter one packed int2 {src, eid} per edge (single 8B store)
__global__ __launch_bounds__(256) void k_scatter(const int* __restrict__ ei,
                                                 int* __restrict__ cursor,
                                                 int2* __restrict__ edata) {
  int e = blockIdx.x * 256 + threadIdx.x;
  if (e < N_EDGES) {
    int dst = ei[N_EDGES + e];
    int pos = atomicAdd(&cursor[dst], 1);
    edata[pos] = make_int2(ei[e], e);
  }
}

// permute ea into CSR order as duplicated fp16 pairs; emit sequential srcs
__global__ __launch_bounds__(256) void k_permea(const int2* __restrict__ edata,
                                                const float* __restrict__ ea,
                                                int* __restrict__ srcs,
                                                uint32_t* __restrict__ ea_dup) {
  int p = blockIdx.x * 256 + threadIdx.x;
  if (p < N_EDGES) {
    int2 d = edata[p];
    srcs[p] = d.x;
    const float* r = &ea[(size_t)d.y * EINC];
    uint32_t* o = &ea_dup[(size_t)p * EINC];
#pragma unroll
    for (int k = 0; k < EINC; ++k) {
      _Float16 v = (_Float16)r[k];
      half2v dv; dv[0] = v; dv[1] = v;
      o[k] = __builtin_bit_cast(uint32_t, dv);
    }
  }
}

// ---------------- merged weight convert (once per launch) ----------------
// [0, 163840): w1t[l][n][k] = W1[l][k][n]   (n<256,k<128)
// [163840, 327680): w2t[l][n][k] = W2[l][k][n]  (n<128,k<256)
// [327680, 337920): eWh = fp16(eW)
__global__ __launch_bounds__(256) void k_cvtw(const float* __restrict__ W1,
                                              const float* __restrict__ W2,
                                              const float* __restrict__ eW,
                                              _Float16* __restrict__ w1t,
                                              _Float16* __restrict__ w2t,
                                              _Float16* __restrict__ eWh) {
  int i = blockIdx.x * 256 + threadIdx.x;
  if (i < 163840) {
    int l = i >> 15, r = i & 32767;
    int n = r >> 7, k = r & 127;
    w1t[i] = (_Float16)W1[(size_t)l * 32768 + k * 256 + n];
  } else if (i < 327680) {
    int j = i - 163840;
    int l = j >> 15, r = j & 32767;
    int n = r >> 8, k = r & 255;
    w2t[j] = (_Float16)W2[(size_t)l * 32768 + k * 128 + n];
  } else if (i < 337920) {
    int j = i - 327680;
    eWh[j] = (_Float16)eW[j];
  }
}

// -------- fused per-node aggregation: fp16 packed math, 2 waves/node --------
// BN2 scale/shift computed in prologue from prev layer's raw stats (inlined bnfin)
__global__ __launch_bounds__(256) void k_aggr(const int* __restrict__ offs,
                                              const int* __restrict__ srcs,
                                              const uint32_t* __restrict__ ea_dup,
                                              const _Float16* __restrict__ eWh,  // [16][128]
                                              const float* __restrict__ eb,     // [128]
                                              const float* __restrict__ epsA, int layer,
                                              const _Float16* __restrict__ hraw,
                                              const float* __restrict__ gsum2,  // prev layer stats
                                              const float* __restrict__ gsq2,
                                              const float* __restrict__ bng,
                                              const float* __restrict__ bnb,
                                              int fuse_bn,
                                              _Float16* __restrict__ z) {
  __shared__ float sP[2 * HD];
  const int w = threadIdx.x >> 6;
  const int lane = threadIdx.x & 63;
  const int nodeIdx = w >> 1, sub = w & 1;
  const int n = blockIdx.x * 2 + nodeIdx;
  const int c0 = lane * 2;

  half2v wph[EINC];
#pragma unroll
  for (int k = 0; k < EINC; ++k) wph[k] = *(const half2v*)&eWh[k * HD + c0];
  half2v ebh; ebh[0] = (_Float16)eb[c0]; ebh[1] = (_Float16)eb[c0 + 1];
  half2v hz; hz[0] = (_Float16)0.f; hz[1] = (_Float16)0.f;
  half2v sch = hz, shh = hz;
  if (fuse_bn) {
    const float invN = 1.0f / (float)N_NODES;
    float m0 = gsum2[c0] * invN, m1 = gsum2[c0 + 1] * invN;
    float v0 = fmaxf(gsq2[c0] * invN - m0 * m0, 0.0f);
    float v1 = fmaxf(gsq2[c0 + 1] * invN - m1 * m1, 0.0f);
    float s0 = bng[c0] * rsqrtf(v0 + BN_EPS);
    float s1 = bng[c0 + 1] * rsqrtf(v1 + BN_EPS);
    sch[0] = (_Float16)s0; sch[1] = (_Float16)s1;
    shh[0] = (_Float16)(bnb[c0] - m0 * s0);
    shh[1] = (_Float16)(bnb[c0 + 1] - m1 * s1);
  }
  const float epsv = 1.0f + epsA[layer];

  f32x2 acc = {0.f, 0.f};
  if (n < N_NODES) {
    int j0 = offs[n], j1 = offs[n + 1];
    int jm = j0 + ((j1 - j0 + 1) >> 1);
    int ja = sub ? jm : j0;
    int jb = sub ? j1 : jm;

    int jj = ja;
    for (; jj + 3 < jb; jj += 4) {
      int ju = __builtin_amdgcn_readfirstlane(jj);
      const int* sj = &srcs[ju];
      int s0 = sj[0], s1 = sj[1], s2 = sj[2], s3 = sj[3];
      const uint32_t* ra = &ea_dup[(size_t)ju * EINC];
      half2v g0 = *(const half2v*)&hraw[(size_t)s0 * HD + c0];
      half2v g1 = *(const half2v*)&hraw[(size_t)s1 * HD + c0];
      half2v g2 = *(const half2v*)&hraw[(size_t)s2 * HD + c0];
      half2v g3 = *(const half2v*)&hraw[(size_t)s3 * HD + c0];
      half2v e0 = ebh, e1 = ebh, e2 = ebh, e3 = ebh;
#pragma unroll
      for (int k = 0; k < EINC; ++k) {
        half2v w2 = wph[k];
        e0 = __builtin_elementwise_fma(h2bc(ra[k]), w2, e0);
        e1 = __builtin_elementwise_fma(h2bc(ra[EINC + k]), w2, e1);
        e2 = __builtin_elementwise_fma(h2bc(ra[2 * EINC + k]), w2, e2);
        e3 = __builtin_elementwise_fma(h2bc(ra[3 * EINC + k]), w2, e3);
      }
      if (fuse_bn) {
        g0 = __builtin_elementwise_max(__builtin_elementwise_fma(g0, sch, shh), hz);
        g1 = __builtin_elementwise_max(__builtin_elementwise_fma(g1, sch, shh), hz);
        g2 = __builtin_elementwise_max(__builtin_elementwise_fma(g2, sch, shh), hz);
        g3 = __builtin_elementwise_max(__builtin_elementwise_fma(g3, sch, shh), hz);
      }
      half2v m0 = __builtin_elementwise_max(g0 + e0, hz);
      half2v m1 = __builtin_elementwise_max(g1 + e1, hz);
      half2v m2 = __builtin_elementwise_max(g2 + e2, hz);
      half2v m3 = __builtin_elementwise_max(g3 + e3, hz);
      acc[0] += (float)m0[0]; acc[1] += (float)m0[1];
      acc[0] += (float)m1[0]; acc[1] += (float)m1[1];
      acc[0] += (float)m2[0]; acc[1] += (float)m2[1];
      acc[0] += (float)m3[0]; acc[1] += (float)m3[1];
    }
    for (; jj < jb; ++jj) {
      int ju = __builtin_amdgcn_readfirstlane(jj);
      int s0 = srcs[ju];
      const uint32_t* ra = &ea_dup[(size_t)ju * EINC];
      half2v g0 = *(const half2v*)&hraw[(size_t)s0 * HD + c0];
      half2v e0 = ebh;
#pragma unroll
      for (int k = 0; k < EINC; ++k)
        e0 = __builtin_elementwise_fma(h2bc(ra[k]), wph[k], e0);
      if (fuse_bn)
        g0 = __builtin_elementwise_max(__builtin_elementwise_fma(g0, sch, shh), hz);
      half2v m0 = __builtin_elementwise_max(g0 + e0, hz);
      acc[0] += (float)m0[0]; acc[1] += (float)m0[1];
    }

    if (!sub) {  // self term
      half2v hv = *(const half2v*)&hraw[(size_t)n * HD + c0];
      if (fuse_bn) hv = __builtin_elementwise_max(__builtin_elementwise_fma(hv, sch, shh), hz);
      acc[0] += epsv * (float)hv[0];
      acc[1] += epsv * (float)hv[1];
    } else {
      sP[nodeIdx * HD + c0] = acc[0];
      sP[nodeIdx * HD + c0 + 1] = acc[1];
    }
  }
  __syncthreads();
  if (n < N_NODES && !sub) {
    acc[0] += sP[nodeIdx * HD + c0];
    acc[1] += sP[nodeIdx * HD + c0 + 1];
    half2v oz; oz[0] = (_Float16)acc[0]; oz[1] = (_Float16)acc[1];
    *(half2v*)&z[(size_t)n * HD + c0] = oz;
  }
}

// ---------- GEMM1 (MFMA fp16): y1h = fp16(z @ W1 + b1) ; col stats ----------
// epilogue: LDS-bounce -> coalesced half8 stores (4 chunks of 32 rows)
__global__ __launch_bounds__(256) void k_gemm1m(const _Float16* __restrict__ z,
                                                const _Float16* __restrict__ w1t, // [256][128]
                                                const float* __restrict__ bias,   // [256]
                                                _Float16* __restrict__ y1h,
                                                float* __restrict__ gsum,
                                                float* __restrict__ gsq) {
  __shared__ char smemRaw[20480];
  _Float16* sA = (_Float16*)smemRaw;              // 128*40 halves = 10240 B
  _Float16* sBT = (_Float16*)(smemRaw + 10240);   // 128*40 halves = 10240 B
  float* sOut = (float*)smemRaw;                  // [32][132] f32 = 16896 B (post-K reuse)
  __shared__ float ssum[128], ssq[128];
  const int tid = threadIdx.x;
  const int lane = tid & 63;
  const int wid = tid >> 6;
  const int wm = wid >> 1, wn = wid & 1;
  const int m0 = blockIdx.x * 128;
  const int n0 = blockIdx.y * 128;

  if (tid < 128) { ssum[tid] = 0.f; ssq[tid] = 0.f; }

  f32x4 acc[4][4];
  const f32x4 zz = {0.f, 0.f, 0.f, 0.f};
#pragma unroll
  for (int a = 0; a < 4; ++a)
#pragma unroll
    for (int b = 0; b < 4; ++b) acc[a][b] = zz;

  const int srow = tid >> 1;
  const int skh = (tid & 1) * 16;

  for (int k0 = 0; k0 < 128; k0 += 32) {
    {
      int n = m0 + srow;
      half8 p0, p1;
      if (n < N_NODES) {
        p0 = *(const half8*)&z[(size_t)n * 128 + k0 + skh];
        p1 = *(const half8*)&z[(size_t)n * 128 + k0 + skh + 8];
      } else {
#pragma unroll
        for (int j = 0; j < 8; ++j) { p0[j] = (_Float16)0.f; p1[j] = (_Float16)0.f; }
      }
      *(half8*)&sA[srow * 40 + skh] = p0;
      *(half8*)&sA[srow * 40 + skh + 8] = p1;
    }
    {
      half8 u0 = *(const half8*)&w1t[(size_t)(n0 + srow) * 128 + k0 + skh];
      half8 u1 = *(const half8*)&w1t[(size_t)(n0 + srow) * 128 + k0 + skh + 8];
      *(half8*)&sBT[srow * 40 + skh] = u0;
      *(half8*)&sBT[srow * 40 + skh + 8] = u1;
    }
    __syncthreads();
    half8 af[4], bf[4];
#pragma unroll
    for (int t = 0; t < 4; ++t) {
      af[t] = *(const half8*)&sA[(wm * 64 + t * 16 + (lane & 15)) * 40 + (lane >> 4) * 8];
      bf[t] = *(const half8*)&sBT[(wn * 64 + t * 16 + (lane & 15)) * 40 + (lane >> 4) * 8];
    }
#pragma unroll
    for (int tm = 0; tm < 4; ++tm)
#pragma unroll
      for (int tn = 0; tn < 4; ++tn)
        acc[tm][tn] = __builtin_amdgcn_mfma_f32_16x16x32_f16(af[tm], bf[tn], acc[tm][tn], 0, 0, 0);
    __syncthreads();
  }

  // ---- stats from registers ----
  float bsv[4];
#pragma unroll
  for (int tn = 0; tn < 4; ++tn) bsv[tn] = bias[n0 + wn * 64 + tn * 16 + (lane & 15)];
  {
    float sacc[4] = {0.f, 0.f, 0.f, 0.f}, qacc[4] = {0.f, 0.f, 0.f, 0.f};
#pragma unroll
    for (int tm = 0; tm < 4; ++tm) {
      int nbase = m0 + wm * 64 + tm * 16 + (lane >> 4) * 4;
#pragma unroll
      for (int r = 0; r < 4; ++r) {
        if (nbase + r < N_NODES) {
#pragma unroll
          for (int tn = 0; tn < 4; ++tn) {
            float v = acc[tm][tn][r] + bsv[tn];
            sacc[tn] += v; qacc[tn] += v * v;
          }
        }
      }
    }
#pragma unroll
    for (int tn = 0; tn < 4; ++tn) {
      int c = wn * 64 + tn * 16 + (lane & 15);
      atomicAdd(&ssum[c], sacc[tn]);
      atomicAdd(&ssq[c], qacc[tn]);
    }
  }

  // ---- chunked vectorized store (4 chunks x 32 rows) ----
  for (int c = 0; c < 4; ++c) {
    __syncthreads();
    if (wm == (c >> 1)) {
#pragma unroll
      for (int t2 = 0; t2 < 2; ++t2) {
        int tm = (c & 1) * 2 + t2;
#pragma unroll
        for (int tn = 0; tn < 4; ++tn)
#pragma unroll
          for (int r = 0; r < 4; ++r)
            sOut[(t2 * 16 + (lane >> 4) * 4 + r) * 132 + wn * 64 + tn * 16 + (lane & 15)] =
                acc[tm][tn][r] + bsv[tn];
      }
    }
    __syncthreads();
    int row = tid >> 3;
    int cb = (tid & 7) * 16;
    int gn = m0 + c * 32 + row;
    if (gn < N_NODES) {
      const float* rp = &sOut[row * 132 + cb];
      half8 o0, o1;
#pragma unroll
      for (int q = 0; q < 8; ++q) o0[q] = (_Float16)rp[q];
#pragma unroll
      for (int q = 0; q < 8; ++q) o1[q] = (_Float16)rp[8 + q];
      *(half8*)&y1h[(size_t)gn * 256 + n0 + cb] = o0;
      *(half8*)&y1h[(size_t)gn * 256 + n0 + cb + 8] = o1;
    }
  }
  __syncthreads();
  if (tid < 128) {
    unsafeAtomicAdd(&gsum[n0 + tid], ssum[tid]);
    unsafeAtomicAdd(&gsq[n0 + tid], ssq[tid]);
  }
}

// ---------- GEMM2 (MFMA fp16): hraw(fp16) = relu(bn1(y1h)) @ W2 + b2 ; col stats ----------
// BN1 scale/shift computed in prologue from gemm1's raw stats (inlined bnfin)
__global__ __launch_bounds__(256) void k_gemm2m(const _Float16* __restrict__ y1h,
                                                const float* __restrict__ gsum1,
                                                const float* __restrict__ gsq1,
                                                const float* __restrict__ g1r,   // [256]
                                                const float* __restrict__ be1r,  // [256]
                                                const _Float16* __restrict__ w2t, // [128][256]
                                                const float* __restrict__ bias,   // [128]
                                                _Float16* __restrict__ y2,
                                                float* __restrict__ gsum,
                                                float* __restrict__ gsq) {
  __shared__ char smemRaw[16896];
  _Float16* sA = (_Float16*)smemRaw;              // 64*40 halves = 5120 B
  _Float16* sBT = (_Float16*)(smemRaw + 5120);    // 128*40 halves = 10240 B
  float* sOut = (float*)smemRaw;                  // [32][132] f32 = 16896 B (post-K reuse)
  __shared__ float ssc[256], ssh[256];
  __shared__ float ssum[128], ssq[128];
  const int tid = threadIdx.x;
  const int lane = tid & 63;
  const int wid = tid >> 6;
  const int wm = wid >> 1, wn = wid & 1;
  const int m0 = blockIdx.x * 64;

  {
    const float invN = 1.0f / (float)N_NODES;
    float m = gsum1[tid] * invN;
    float v = fmaxf(gsq1[tid] * invN - m * m, 0.0f);
    float s = g1r[tid] * rsqrtf(v + BN_EPS);
    ssc[tid] = s;
    ssh[tid] = be1r[tid] - m * s;
  }
  if (tid < 128) { ssum[tid] = 0.f; ssq[tid] = 0.f; }
  __syncthreads();

  f32x4 acc[2][4];
  const f32x4 zz = {0.f, 0.f, 0.f, 0.f};
#pragma unroll
  for (int a = 0; a < 2; ++a)
#pragma unroll
    for (int b = 0; b < 4; ++b) acc[a][b] = zz;

  const int arow = tid >> 2;
  const int akq = (tid & 3) * 8;
  const int brow = tid >> 1;
  const int bkh = (tid & 1) * 16;

  for (int k0 = 0; k0 < 256; k0 += 32) {
    {
      int n = m0 + arow;
      half8 p;
      if (n < N_NODES) {
        half8 yv = *(const half8*)&y1h[(size_t)n * 256 + k0 + akq];
#pragma unroll
        for (int j = 0; j < 8; ++j) {
          float v = fmaxf((float)yv[j] * ssc[k0 + akq + j] + ssh[k0 + akq + j], 0.f);
          p[j] = (_Float16)v;
        }
      } else {
#pragma unroll
        for (int j = 0; j < 8; ++j) p[j] = (_Float16)0.f;
      }
      *(half8*)&sA[arow * 40 + akq] = p;
    }
    {
      half8 u0 = *(const half8*)&w2t[(size_t)brow * 256 + k0 + bkh];
      half8 u1 = *(const half8*)&w2t[(size_t)brow * 256 + k0 + bkh + 8];
      *(half8*)&sBT[brow * 40 + bkh] = u0;
      *(half8*)&sBT[brow * 40 + bkh + 8] = u1;
    }
    __syncthreads();
    half8 af[2], bf[4];
#pragma unroll
    for (int t = 0; t < 2; ++t)
      af[t] = *(const half8*)&sA[(wm * 32 + t * 16 + (lane & 15)) * 40 + (lane >> 4) * 8];
#pragma unroll
    for (int t = 0; t < 4; ++t)
      bf[t] = *(const half8*)&sBT[(wn * 64 + t * 16 + (lane & 15)) * 40 + (lane >> 4) * 8];
#pragma unroll
    for (int tm = 0; tm < 2; ++tm)
#pragma unroll
      for (int tn = 0; tn < 4; ++tn)
        acc[tm][tn] = __builtin_amdgcn_mfma_f32_16x16x32_f16(af[tm], bf[tn], acc[tm][tn], 0, 0, 0);
    __syncthreads();
  }

  // ---- stats from registers ----
  float bsv[4];
#pragma unroll
  for (int tn = 0; tn < 4; ++tn) bsv[tn] = bias[wn * 64 + tn * 16 + (lane & 15)];
  {
    float sacc[4] = {0.f, 0.f, 0.f, 0.f}, qacc[4] = {0.f, 0.f, 0.f, 0.f};
#pragma unroll
    for (int tm = 0; tm < 2; ++tm) {
      int nbase = m0 + wm * 32 + tm * 16 + (lane >> 4) * 4;
#pragma unroll
      for (int r = 0; r < 4; ++r) {
        if (nbase + r < N_NODES) {
#pragma unroll
          for (int tn = 0; tn < 4; ++tn) {
            float v = acc[tm][tn][r] + bsv[tn];
            sacc[tn] += v; qacc[tn] += v * v;
          }
        }
      }
    }
#pragma unroll
    for (int tn = 0; tn < 4; ++tn) {
      int c = wn * 64 + tn * 16 + (lane & 15);
      atomicAdd(&ssum[c], sacc[tn]);
      atomicAdd(&ssq[c], qacc[tn]);
    }
  }

  // ---- chunked vectorized store (2 chunks x 32 rows) ----
  for (int c = 0; c < 2; ++c) {
    __syncthreads();
    if (wm == c) {
#pragma unroll
      for (int tm = 0; tm < 2; ++tm)
#pragma unroll
        for (int tn = 0; tn < 4; ++tn)
#pragma unroll
          for (int r = 0; r < 4; ++r)
            sOut[(tm * 16 + (lane >> 4) * 4 + r) * 132 + wn * 64 + tn * 16 + (lane & 15)] =
                acc[tm][tn][r] + bsv[tn];
    }
    __syncthreads();
    int row = tid >> 3;
    int cb = (tid & 7) * 16;
    int gn = m0 + c * 32 + row;
    if (gn < N_NODES) {
      const float* rp = &sOut[row * 132 + cb];
      half8 o0, o1;
#pragma unroll
      for (int q = 0; q < 8; ++q) o0[q] = (_Float16)rp[q];
#pragma unroll
      for (int q = 0; q < 8; ++q) o1[q] = (_Float16)rp[8 + q];
      *(half8*)&y2[(size_t)gn * 128 + cb] = o0;
      *(half8*)&y2[(size_t)gn * 128 + cb + 8] = o1;
    }
  }
  __syncthreads();
  if (tid < 128) {
    unsafeAtomicAdd(&gsum[tid], ssum[tid]);
    unsafeAtomicAdd(&gsq[tid], ssq[tid]);
  }
}

// ---------------- pooling with inlined final BN ----------------
__global__ void k_goff(const int* __restrict__ batch, int* __restrict__ goff) {
  int g = blockIdx.x * blockDim.x + threadIdx.x;
  if (g <= NG) {
    if (g == NG) { goff[g] = N_NODES; return; }
    int lo = 0, hi = N_NODES;
    while (lo < hi) { int mid = (lo + hi) >> 1; if (batch[mid] < g) lo = mid + 1; else hi = mid; }
    goff[g] = lo;
  }
}

__global__ __launch_bounds__(256) void k_poolseg(const _Float16* __restrict__ y2raw,
                                                 const float* __restrict__ gsum2,
                                                 const float* __restrict__ gsq2,
                                                 const float* __restrict__ bng,
                                                 const float* __restrict__ bnb,
                                                 const int* __restrict__ goff,
                                                 float* __restrict__ pooled) {
  __shared__ float sred[256];
  int g = blockIdx.x;
  int c = threadIdx.x & 127;
  int half = threadIdx.x >> 7;
  int n0 = goff[g], n1 = goff[g + 1];
  float s = 0.f;
  for (int n = n0 + half; n < n1; n += 2) s += (float)y2raw[(size_t)n * HD + c];
  sred[threadIdx.x] = s;
  __syncthreads();
  if (threadIdx.x < 128) {
    const float invN = 1.0f / (float)N_NODES;
    float m = gsum2[threadIdx.x] * invN;
    float v = fmaxf(gsq2[threadIdx.x] * invN - m * m, 0.0f);
    float scv = bng[threadIdx.x] * rsqrtf(v + BN_EPS);
    float shv = bnb[threadIdx.x] - m * scv;
    float tot = sred[threadIdx.x] + sred[threadIdx.x + 128];
    float cntf = fmaxf((float)(n1 - n0), 1.0f);
    pooled[g * HD + threadIdx.x] = scv * (tot / cntf) + shv;
  }
}

// ---------------- final GEMM ----------------
__global__ __launch_bounds__(128) void k_final(const float* __restrict__ pooled,
                                               const float* __restrict__ oW,
                                               const float* __restrict__ ob,
                                               float* __restrict__ out) {
  __shared__ float sP[HD];
  int g = blockIdx.x;
  int c = threadIdx.x;
  sP[c] = pooled[g * HD + c];
  __syncthreads();
  float acc = ob[c];
#pragma unroll 8
  for (int k = 0; k < HD; ++k) acc += sP[k] * oW[k * HD + c];
  out[g * HD + c] = acc;
}

extern "C" void kernel_launch(void* const* d_in, const int* in_sizes, int n_in,
                              void* d_out, int out_size, void* d_ws, size_t ws_size,
                              hipStream_t stream) {
  const int* x = (const int*)d_in[0];
  const int* ei = (const int*)d_in[1];
  const float* ea = (const float*)d_in[2];
  const int* batch = (const int*)d_in[3];
  const float* emb = (const float*)d_in[4];
  const float* eW = (const float*)d_in[5];
  const float* eb = (const float*)d_in[6];
  const float* epsA = (const float*)d_in[7];
  const float* W1 = (const float*)d_in[8];
  const float* b1 = (const float*)d_in[9];
  const float* g1 = (const float*)d_in[10];
  const float* be1 = (const float*)d_in[11];
  const float* W2 = (const float*)d_in[12];
  const float* b2 = (const float*)d_in[13];
  const float* bng = (const float*)d_in[14];
  const float* bnb = (const float*)d_in[15];
  const float* oW = (const float*)d_in[16];
  const float* ob = (const float*)d_in[17];
  float* out = (float*)d_out;

  // ----- workspace layout: ints first, then floats -----
  int* ip = (int*)d_ws;
  int* deg = ip;                              // 50,000
  int* incl = deg + 50000;                    // 50,000
  int* offs = incl + 50000;                   // 50,001
  int* cursor = offs + 50001;                 // 50,000
  int2* edata = (int2*)(cursor + 50000 + 1);  // 800,000 int2 (8B aligned)
  int* srcs = (int*)(edata + 800000);         // 800,000
  int* bsum = srcs + 800000;                  // 200
  int* goff = bsum + 200;                     // 513
  float* fp = (float*)(ip + 2600716);
  _Float16* h = (_Float16*)fp;                       // 6.4M halves (3.2M float slots)
  _Float16* zbuf = (_Float16*)(fp + 3200000);        // 6.4M halves
  _Float16* y1h = (_Float16*)(fp + 6400000);         // 12.8M halves (6.4M float slots)
  uint32_t* ea_dup = (uint32_t*)(fp + 12800000);     // 12.8M u32
  float* statsA = fp + 25600000;              // 5 * 768 arena
  float* pooled = statsA + 3840;              // 65,536
  _Float16* w1t = (_Float16*)(pooled + 65536);       // 163,840 halves
  _Float16* w2t = w1t + 163840;                      // 163,840 halves
  _Float16* eWh = w2t + 163840;                      // 10,240 halves

  const int edge_blocks = (N_EDGES + 255) / 256;
  const int node_blocks = (N_NODES + 255) / 256;

  k_embed<<<(N_NODES * 16 + 255) / 256, 256, 0, stream>>>(x, emb, h);

  // CSR build + permuted fp16 ea + weight conversion + stats arena zero (once per launch)
  hipMemsetAsync(deg, 0, 50000 * sizeof(int), stream);
  hipMemsetAsync(statsA, 0, 3840 * sizeof(float), stream);
  k_hist<<<edge_blocks, 256, 0, stream>>>(ei, deg);
  k_scan1<<<node_blocks, 256, 0, stream>>>(deg, incl, bsum);
  k_scan2<<<1, 256, 0, stream>>>(bsum, node_blocks);
  k_scan3<<<node_blocks, 256, 0, stream>>>(deg, incl, bsum, offs, cursor);
  k_scatter<<<edge_blocks, 256, 0, stream>>>(ei, cursor, edata);
  k_permea<<<edge_blocks, 256, 0, stream>>>(edata, ea, srcs, ea_dup);
  k_goff<<<3, 256, 0, stream>>>(batch, goff);
  k_cvtw<<<(337920 + 255) / 256, 256, 0, stream>>>(W1, W2, eW, w1t, w2t, eWh);

  for (int l = 0; l < NLAYERS; ++l) {
    float* st = statsA + (size_t)l * 768;         // gsum1 | gsq1 (256+256)
    float* st2 = st + 512;                        // gsum2 | gsq2 (128+128)
    const float* pst2 = statsA + (size_t)(l - 1) * 768 + 512;  // prev layer gemm2 stats
    k_aggr<<<(N_NODES + 1) / 2, 256, 0, stream>>>(offs, srcs, ea_dup,
                                                  eWh + (size_t)l * EINC * HD, eb + l * HD,
                                                  epsA, l, h,
                                                  (l > 0) ? pst2 : statsA, (l > 0) ? pst2 + 128 : statsA,
                                                  bng + (l > 0 ? (l - 1) : 0) * HD,
                                                  bnb + (l > 0 ? (l - 1) : 0) * HD,
                                                  (l > 0) ? 1 : 0, zbuf);
    k_gemm1m<<<dim3(391, 2), 256, 0, stream>>>(zbuf, w1t + (size_t)l * 32768,
                                               b1 + l * 256, y1h, st, st + 256);
    k_gemm2m<<<782, 256, 0, stream>>>(y1h, st, st + 256, g1 + l * 256, be1 + l * 256,
                                      w2t + (size_t)l * 32768, b2 + l * HD, h,
                                      st2, st2 + 128);
  }

  {
    const float* lst2 = statsA + (size_t)(NLAYERS - 1) * 768 + 512;
    k_poolseg<<<NG, 256, 0, stream>>>(h, lst2, lst2 + 128,
                                      bng + (NLAYERS - 1) * HD, bnb + (NLAYERS - 1) * HD,
                                      goff, pooled);
  }
  k_final<<<NG, 128, 0, stream>>>(pooled, oW, ob, out);
}

// Round 18
// 917.005 us; speedup vs baseline: 1.1604x; 1.0559x over previous
//
#include <hip/hip_runtime.h>
#include <hip/hip_fp16.h>

#define N_NODES 50000
#define N_EDGES 800000
#define HD 128
#define NLAYERS 5
#define EINC 16
#define NG 512
#define BN_EPS 1e-5f

typedef _Float16 half8 __attribute__((ext_vector_type(8)));
typedef _Float16 half2v __attribute__((ext_vector_type(2)));
typedef float f32x4 __attribute__((ext_vector_type(4)));
typedef float f32x2 __attribute__((ext_vector_type(2)));

__device__ inline half2v h2bc(uint32_t u) { return __builtin_bit_cast(half2v, u); }

// ---------------- embedding: h (fp16) = emb[x[n]] ----------------
__global__ __launch_bounds__(256) void k_embed(const int* __restrict__ x,
                                               const float* __restrict__ emb,
                                               _Float16* __restrict__ h) {
  int i = blockIdx.x * 256 + threadIdx.x;       // 8-ch groups
  if (i < N_NODES * 16) {
    int n = i >> 4, cv = i & 15;
    const float* src = &emb[(size_t)x[n] * HD + cv * 8];
    float4 a0 = *(const float4*)&src[0];
    float4 a1 = *(const float4*)&src[4];
    half8 p;
    p[0] = (_Float16)a0.x; p[1] = (_Float16)a0.y; p[2] = (_Float16)a0.z; p[3] = (_Float16)a0.w;
    p[4] = (_Float16)a1.x; p[5] = (_Float16)a1.y; p[6] = (_Float16)a1.z; p[7] = (_Float16)a1.w;
    *(half8*)&h[(size_t)n * HD + cv * 8] = p;
  }
}

// ---------------- CSR build ----------------
__global__ __launch_bounds__(256) void k_hist(const int* __restrict__ ei,
                                              int* __restrict__ deg) {
  int e = blockIdx.x * 256 + threadIdx.x;
  if (e < N_EDGES) atomicAdd(&deg[ei[N_EDGES + e]], 1);
}

__global__ __launch_bounds__(256) void k_scan1(const int* __restrict__ deg,
                                               int* __restrict__ incl,
                                               int* __restrict__ bsum) {
  __shared__ int s[256];
  int i = blockIdx.x * 256 + threadIdx.x;
  int v = (i < N_NODES) ? deg[i] : 0;
  s[threadIdx.x] = v;
  __syncthreads();
  for (int d = 1; d < 256; d <<= 1) {
    int t = (threadIdx.x >= d) ? s[threadIdx.x - d] : 0;
    __syncthreads();
    s[threadIdx.x] += t;
    __syncthreads();
  }
  if (i < N_NODES) incl[i] = s[threadIdx.x];
  if (threadIdx.x == 255) bsum[blockIdx.x] = s[255];
}

__global__ void k_scan2(int* __restrict__ bsum, int nb) {
  __shared__ int s[256];
  int v = (threadIdx.x < nb) ? bsum[threadIdx.x] : 0;
  s[threadIdx.x] = v;
  __syncthreads();
  for (int d = 1; d < 256; d <<= 1) {
    int t = (threadIdx.x >= d) ? s[threadIdx.x - d] : 0;
    __syncthreads();
    s[threadIdx.x] += t;
    __syncthreads();
  }
  if (threadIdx.x < nb) bsum[threadIdx.x] = s[threadIdx.x];
}

__global__ __launch_bounds__(256) void k_scan3(const int* __restrict__ deg,
                                               const int* __restrict__ incl,
                                               const int* __restrict__ bsum,
                                               int* __restrict__ offs,
                                               int* __restrict__ cursor) {
  int i = blockIdx.x * 256 + threadIdx.x;
  if (i < N_NODES) {
    int base = (blockIdx.x > 0) ? bsum[blockIdx.x - 1] : 0;
    int start = base + incl[i] - deg[i];
    offs[i] = start;
    cursor[i] = start;
    if (i == N_NODES - 1) offs[N_NODES] = N_EDGES;
  }
}

// scatter one packed int2 {src, eid} per edge (single 8B store)
__global__ __launch_bounds__(256) void k_scatter(const int* __restrict__ ei,
                                                 int* __restrict__ cursor,
                                                 int2* __restrict__ edata) {
  int e = blockIdx.x * 256 + threadIdx.x;
  if (e < N_EDGES) {
    int dst = ei[N_EDGES + e];
    int pos = atomicAdd(&cursor[dst], 1);
    edata[pos] = make_int2(ei[e], e);
  }
}

// permute ea into CSR order as plain fp16 rows (16 halves = 32B); emit sequential srcs
__global__ __launch_bounds__(256) void k_permea(const int2* __restrict__ edata,
                                                const float* __restrict__ ea,
                                                int* __restrict__ srcs,
                                                _Float16* __restrict__ ea_h) {
  int p = blockIdx.x * 256 + threadIdx.x;
  if (p < N_EDGES) {
    int2 d = edata[p];
    srcs[p] = d.x;
    const float* r = &ea[(size_t)d.y * EINC];
    half8 o0, o1;
#pragma unroll
    for (int k = 0; k < 8; ++k) { o0[k] = (_Float16)r[k]; o1[k] = (_Float16)r[8 + k]; }
    *(half8*)&ea_h[(size_t)p * EINC] = o0;
    *(half8*)&ea_h[(size_t)p * EINC + 8] = o1;
  }
}

// ---------------- merged weight convert (once per launch) ----------------
// [0, 163840): w1t[l][n][k] = W1[l][k][n]   (n<256,k<128)
// [163840, 327680): w2t[l][n][k] = W2[l][k][n]  (n<128,k<256)
// [327680, 337920): eWh = fp16(eW)
__global__ __launch_bounds__(256) void k_cvtw(const float* __restrict__ W1,
                                              const float* __restrict__ W2,
                                              const float* __restrict__ eW,
                                              _Float16* __restrict__ w1t,
                                              _Float16* __restrict__ w2t,
                                              _Float16* __restrict__ eWh) {
  int i = blockIdx.x * 256 + threadIdx.x;
  if (i < 163840) {
    int l = i >> 15, r = i & 32767;
    int n = r >> 7, k = r & 127;
    w1t[i] = (_Float16)W1[(size_t)l * 32768 + k * 256 + n];
  } else if (i < 327680) {
    int j = i - 163840;
    int l = j >> 15, r = j & 32767;
    int n = r >> 8, k = r & 255;
    w2t[j] = (_Float16)W2[(size_t)l * 32768 + k * 128 + n];
  } else if (i < 337920) {
    int j = i - 327680;
    eWh[j] = (_Float16)eW[j];
  }
}

// -------- fused per-node aggregation: fp16 packed math, 2 waves/node --------
// ea loaded as plain fp16 k-pairs; broadcast via shufflevector (op_sel on v_pk_fma)
__global__ __launch_bounds__(256) void k_aggr(const int* __restrict__ offs,
                                              const int* __restrict__ srcs,
                                              const _Float16* __restrict__ ea_h,  // [N_EDGES][16]
                                              const _Float16* __restrict__ eWh,   // [16][128]
                                              const float* __restrict__ eb,      // [128]
                                              const float* __restrict__ epsA, int layer,
                                              const _Float16* __restrict__ hraw,
                                              const float* __restrict__ gsum2,   // prev layer stats
                                              const float* __restrict__ gsq2,
                                              const float* __restrict__ bng,
                                              const float* __restrict__ bnb,
                                              int fuse_bn,
                                              _Float16* __restrict__ z) {
  __shared__ float sP[2 * HD];
  const int w = threadIdx.x >> 6;
  const int lane = threadIdx.x & 63;
  const int nodeIdx = w >> 1, sub = w & 1;
  const int n = blockIdx.x * 2 + nodeIdx;
  const int c0 = lane * 2;

  half2v wph[EINC];
#pragma unroll
  for (int k = 0; k < EINC; ++k) wph[k] = *(const half2v*)&eWh[k * HD + c0];
  half2v ebh; ebh[0] = (_Float16)eb[c0]; ebh[1] = (_Float16)eb[c0 + 1];
  half2v hz; hz[0] = (_Float16)0.f; hz[1] = (_Float16)0.f;
  half2v sch = hz, shh = hz;
  if (fuse_bn) {
    const float invN = 1.0f / (float)N_NODES;
    float m0 = gsum2[c0] * invN, m1 = gsum2[c0 + 1] * invN;
    float v0 = fmaxf(gsq2[c0] * invN - m0 * m0, 0.0f);
    float v1 = fmaxf(gsq2[c0 + 1] * invN - m1 * m1, 0.0f);
    float s0 = bng[c0] * rsqrtf(v0 + BN_EPS);
    float s1 = bng[c0 + 1] * rsqrtf(v1 + BN_EPS);
    sch[0] = (_Float16)s0; sch[1] = (_Float16)s1;
    shh[0] = (_Float16)(bnb[c0] - m0 * s0);
    shh[1] = (_Float16)(bnb[c0 + 1] - m1 * s1);
  }
  const float epsv = 1.0f + epsA[layer];

  f32x2 acc = {0.f, 0.f};
  if (n < N_NODES) {
    int j0 = offs[n], j1 = offs[n + 1];
    int jm = j0 + ((j1 - j0 + 1) >> 1);
    int ja = sub ? jm : j0;
    int jb = sub ? j1 : jm;

    int jj = ja;
    for (; jj + 3 < jb; jj += 4) {
      int ju = __builtin_amdgcn_readfirstlane(jj);
      const int* sj = &srcs[ju];
      int s0 = sj[0], s1 = sj[1], s2 = sj[2], s3 = sj[3];
      const uint32_t* ra = &((const uint32_t*)&ea_h[(size_t)ju * EINC])[0];  // 8 u32 / edge
      half2v g0 = *(const half2v*)&hraw[(size_t)s0 * HD + c0];
      half2v g1 = *(const half2v*)&hraw[(size_t)s1 * HD + c0];
      half2v g2 = *(const half2v*)&hraw[(size_t)s2 * HD + c0];
      half2v g3 = *(const half2v*)&hraw[(size_t)s3 * HD + c0];
      half2v e0 = ebh, e1 = ebh, e2 = ebh, e3 = ebh;
#pragma unroll
      for (int i = 0; i < 8; ++i) {
        half2v a0v = h2bc(ra[i]);
        half2v a1v = h2bc(ra[8 + i]);
        half2v a2v = h2bc(ra[16 + i]);
        half2v a3v = h2bc(ra[24 + i]);
        half2v w2a = wph[2 * i], w2b = wph[2 * i + 1];
        e0 = __builtin_elementwise_fma(__builtin_shufflevector(a0v, a0v, 0, 0), w2a, e0);
        e0 = __builtin_elementwise_fma(__builtin_shufflevector(a0v, a0v, 1, 1), w2b, e0);
        e1 = __builtin_elementwise_fma(__builtin_shufflevector(a1v, a1v, 0, 0), w2a, e1);
        e1 = __builtin_elementwise_fma(__builtin_shufflevector(a1v, a1v, 1, 1), w2b, e1);
        e2 = __builtin_elementwise_fma(__builtin_shufflevector(a2v, a2v, 0, 0), w2a, e2);
        e2 = __builtin_elementwise_fma(__builtin_shufflevector(a2v, a2v, 1, 1), w2b, e2);
        e3 = __builtin_elementwise_fma(__builtin_shufflevector(a3v, a3v, 0, 0), w2a, e3);
        e3 = __builtin_elementwise_fma(__builtin_shufflevector(a3v, a3v, 1, 1), w2b, e3);
      }
      if (fuse_bn) {
        g0 = __builtin_elementwise_max(__builtin_elementwise_fma(g0, sch, shh), hz);
        g1 = __builtin_elementwise_max(__builtin_elementwise_fma(g1, sch, shh), hz);
        g2 = __builtin_elementwise_max(__builtin_elementwise_fma(g2, sch, shh), hz);
        g3 = __builtin_elementwise_max(__builtin_elementwise_fma(g3, sch, shh), hz);
      }
      half2v m0 = __builtin_elementwise_max(g0 + e0, hz);
      half2v m1 = __builtin_elementwise_max(g1 + e1, hz);
      half2v m2 = __builtin_elementwise_max(g2 + e2, hz);
      half2v m3 = __builtin_elementwise_max(g3 + e3, hz);
      acc[0] += (float)m0[0]; acc[1] += (float)m0[1];
      acc[0] += (float)m1[0]; acc[1] += (float)m1[1];
      acc[0] += (float)m2[0]; acc[1] += (float)m2[1];
      acc[0] += (float)m3[0]; acc[1] += (float)m3[1];
    }
    for (; jj < jb; ++jj) {
      int ju = __builtin_amdgcn_readfirstlane(jj);
      int s0 = srcs[ju];
      const uint32_t* ra = (const uint32_t*)&ea_h[(size_t)ju * EINC];
      half2v g0 = *(const half2v*)&hraw[(size_t)s0 * HD + c0];
      half2v e0 = ebh;
#pragma unroll
      for (int i = 0; i < 8; ++i) {
        half2v av = h2bc(ra[i]);
        e0 = __builtin_elementwise_fma(__builtin_shufflevector(av, av, 0, 0), wph[2 * i], e0);
        e0 = __builtin_elementwise_fma(__builtin_shufflevector(av, av, 1, 1), wph[2 * i + 1], e0);
      }
      if (fuse_bn)
        g0 = __builtin_elementwise_max(__builtin_elementwise_fma(g0, sch, shh), hz);
      half2v m0 = __builtin_elementwise_max(g0 + e0, hz);
      acc[0] += (float)m0[0]; acc[1] += (float)m0[1];
    }

    if (!sub) {  // self term
      half2v hv = *(const half2v*)&hraw[(size_t)n * HD + c0];
      if (fuse_bn) hv = __builtin_elementwise_max(__builtin_elementwise_fma(hv, sch, shh), hz);
      acc[0] += epsv * (float)hv[0];
      acc[1] += epsv * (float)hv[1];
    } else {
      sP[nodeIdx * HD + c0] = acc[0];
      sP[nodeIdx * HD + c0 + 1] = acc[1];
    }
  }
  __syncthreads();
  if (n < N_NODES && !sub) {
    acc[0] += sP[nodeIdx * HD + c0];
    acc[1] += sP[nodeIdx * HD + c0 + 1];
    half2v oz; oz[0] = (_Float16)acc[0]; oz[1] = (_Float16)acc[1];
    *(half2v*)&z[(size_t)n * HD + c0] = oz;
  }
}

// ---------- GEMM1 (MFMA fp16): y1h = fp16(z @ W1 + b1) ; col stats ----------
// epilogue: LDS-bounce -> coalesced half8 stores (4 chunks of 32 rows)
__global__ __launch_bounds__(256) void k_gemm1m(const _Float16* __restrict__ z,
                                                const _Float16* __restrict__ w1t, // [256][128]
                                                const float* __restrict__ bias,   // [256]
                                                _Float16* __restrict__ y1h,
                                                float* __restrict__ gsum,
                                                float* __restrict__ gsq) {
  __shared__ char smemRaw[20480];
  _Float16* sA = (_Float16*)smemRaw;              // 128*40 halves = 10240 B
  _Float16* sBT = (_Float16*)(smemRaw + 10240);   // 128*40 halves = 10240 B
  float* sOut = (float*)smemRaw;                  // [32][132] f32 = 16896 B (post-K reuse)
  __shared__ float ssum[128], ssq[128];
  const int tid = threadIdx.x;
  const int lane = tid & 63;
  const int wid = tid >> 6;
  const int wm = wid >> 1, wn = wid & 1;
  const int m0 = blockIdx.x * 128;
  const int n0 = blockIdx.y * 128;

  if (tid < 128) { ssum[tid] = 0.f; ssq[tid] = 0.f; }

  f32x4 acc[4][4];
  const f32x4 zz = {0.f, 0.f, 0.f, 0.f};
#pragma unroll
  for (int a = 0; a < 4; ++a)
#pragma unroll
    for (int b = 0; b < 4; ++b) acc[a][b] = zz;

  const int srow = tid >> 1;
  const int skh = (tid & 1) * 16;

  for (int k0 = 0; k0 < 128; k0 += 32) {
    {
      int n = m0 + srow;
      half8 p0, p1;
      if (n < N_NODES) {
        p0 = *(const half8*)&z[(size_t)n * 128 + k0 + skh];
        p1 = *(const half8*)&z[(size_t)n * 128 + k0 + skh + 8];
      } else {
#pragma unroll
        for (int j = 0; j < 8; ++j) { p0[j] = (_Float16)0.f; p1[j] = (_Float16)0.f; }
      }
      *(half8*)&sA[srow * 40 + skh] = p0;
      *(half8*)&sA[srow * 40 + skh + 8] = p1;
    }
    {
      half8 u0 = *(const half8*)&w1t[(size_t)(n0 + srow) * 128 + k0 + skh];
      half8 u1 = *(const half8*)&w1t[(size_t)(n0 + srow) * 128 + k0 + skh + 8];
      *(half8*)&sBT[srow * 40 + skh] = u0;
      *(half8*)&sBT[srow * 40 + skh + 8] = u1;
    }
    __syncthreads();
    half8 af[4], bf[4];
#pragma unroll
    for (int t = 0; t < 4; ++t) {
      af[t] = *(const half8*)&sA[(wm * 64 + t * 16 + (lane & 15)) * 40 + (lane >> 4) * 8];
      bf[t] = *(const half8*)&sBT[(wn * 64 + t * 16 + (lane & 15)) * 40 + (lane >> 4) * 8];
    }
#pragma unroll
    for (int tm = 0; tm < 4; ++tm)
#pragma unroll
      for (int tn = 0; tn < 4; ++tn)
        acc[tm][tn] = __builtin_amdgcn_mfma_f32_16x16x32_f16(af[tm], bf[tn], acc[tm][tn], 0, 0, 0);
    __syncthreads();
  }

  // ---- stats from registers ----
  float bsv[4];
#pragma unroll
  for (int tn = 0; tn < 4; ++tn) bsv[tn] = bias[n0 + wn * 64 + tn * 16 + (lane & 15)];
  {
    float sacc[4] = {0.f, 0.f, 0.f, 0.f}, qacc[4] = {0.f, 0.f, 0.f, 0.f};
#pragma unroll
    for (int tm = 0; tm < 4; ++tm) {
      int nbase = m0 + wm * 64 + tm * 16 + (lane >> 4) * 4;
#pragma unroll
      for (int r = 0; r < 4; ++r) {
        if (nbase + r < N_NODES) {
#pragma unroll
          for (int tn = 0; tn < 4; ++tn) {
            float v = acc[tm][tn][r] + bsv[tn];
            sacc[tn] += v; qacc[tn] += v * v;
          }
        }
      }
    }
#pragma unroll
    for (int tn = 0; tn < 4; ++tn) {
      int c = wn * 64 + tn * 16 + (lane & 15);
      atomicAdd(&ssum[c], sacc[tn]);
      atomicAdd(&ssq[c], qacc[tn]);
    }
  }

  // ---- chunked vectorized store (4 chunks x 32 rows) ----
  for (int c = 0; c < 4; ++c) {
    __syncthreads();
    if (wm == (c >> 1)) {
#pragma unroll
      for (int t2 = 0; t2 < 2; ++t2) {
        int tm = (c & 1) * 2 + t2;
#pragma unroll
        for (int tn = 0; tn < 4; ++tn)
#pragma unroll
          for (int r = 0; r < 4; ++r)
            sOut[(t2 * 16 + (lane >> 4) * 4 + r) * 132 + wn * 64 + tn * 16 + (lane & 15)] =
                acc[tm][tn][r] + bsv[tn];
      }
    }
    __syncthreads();
    int row = tid >> 3;
    int cb = (tid & 7) * 16;
    int gn = m0 + c * 32 + row;
    if (gn < N_NODES) {
      const float* rp = &sOut[row * 132 + cb];
      half8 o0, o1;
#pragma unroll
      for (int q = 0; q < 8; ++q) o0[q] = (_Float16)rp[q];
#pragma unroll
      for (int q = 0; q < 8; ++q) o1[q] = (_Float16)rp[8 + q];
      *(half8*)&y1h[(size_t)gn * 256 + n0 + cb] = o0;
      *(half8*)&y1h[(size_t)gn * 256 + n0 + cb + 8] = o1;
    }
  }
  __syncthreads();
  if (tid < 128) {
    unsafeAtomicAdd(&gsum[n0 + tid], ssum[tid]);
    unsafeAtomicAdd(&gsq[n0 + tid], ssq[tid]);
  }
}

// ---------- GEMM2 (MFMA fp16): hraw(fp16) = relu(bn1(y1h)) @ W2 + b2 ; col stats ----------
// BN1 scale/shift computed in prologue from gemm1's raw stats (inlined bnfin)
__global__ __launch_bounds__(256) void k_gemm2m(const _Float16* __restrict__ y1h,
                                                const float* __restrict__ gsum1,
                                                const float* __restrict__ gsq1,
                                                const float* __restrict__ g1r,   // [256]
                                                const float* __restrict__ be1r,  // [256]
                                                const _Float16* __restrict__ w2t, // [128][256]
                                                const float* __restrict__ bias,   // [128]
                                                _Float16* __restrict__ y2,
                                                float* __restrict__ gsum,
                                                float* __restrict__ gsq) {
  __shared__ char smemRaw[16896];
  _Float16* sA = (_Float16*)smemRaw;              // 64*40 halves = 5120 B
  _Float16* sBT = (_Float16*)(smemRaw + 5120);    // 128*40 halves = 10240 B
  float* sOut = (float*)smemRaw;                  // [32][132] f32 = 16896 B (post-K reuse)
  __shared__ float ssc[256], ssh[256];
  __shared__ float ssum[128], ssq[128];
  const int tid = threadIdx.x;
  const int lane = tid & 63;
  const int wid = tid >> 6;
  const int wm = wid >> 1, wn = wid & 1;
  const int m0 = blockIdx.x * 64;

  {
    const float invN = 1.0f / (float)N_NODES;
    float m = gsum1[tid] * invN;
    float v = fmaxf(gsq1[tid] * invN - m * m, 0.0f);
    float s = g1r[tid] * rsqrtf(v + BN_EPS);
    ssc[tid] = s;
    ssh[tid] = be1r[tid] - m * s;
  }
  if (tid < 128) { ssum[tid] = 0.f; ssq[tid] = 0.f; }
  __syncthreads();

  f32x4 acc[2][4];
  const f32x4 zz = {0.f, 0.f, 0.f, 0.f};
#pragma unroll
  for (int a = 0; a < 2; ++a)
#pragma unroll
    for (int b = 0; b < 4; ++b) acc[a][b] = zz;

  const int arow = tid >> 2;
  const int akq = (tid & 3) * 8;
  const int brow = tid >> 1;
  const int bkh = (tid & 1) * 16;

  for (int k0 = 0; k0 < 256; k0 += 32) {
    {
      int n = m0 + arow;
      half8 p;
      if (n < N_NODES) {
        half8 yv = *(const half8*)&y1h[(size_t)n * 256 + k0 + akq];
#pragma unroll
        for (int j = 0; j < 8; ++j) {
          float v = fmaxf((float)yv[j] * ssc[k0 + akq + j] + ssh[k0 + akq + j], 0.f);
          p[j] = (_Float16)v;
        }
      } else {
#pragma unroll
        for (int j = 0; j < 8; ++j) p[j] = (_Float16)0.f;
      }
      *(half8*)&sA[arow * 40 + akq] = p;
    }
    {
      half8 u0 = *(const half8*)&w2t[(size_t)brow * 256 + k0 + bkh];
      half8 u1 = *(const half8*)&w2t[(size_t)brow * 256 + k0 + bkh + 8];
      *(half8*)&sBT[brow * 40 + bkh] = u0;
      *(half8*)&sBT[brow * 40 + bkh + 8] = u1;
    }
    __syncthreads();
    half8 af[2], bf[4];
#pragma unroll
    for (int t = 0; t < 2; ++t)
      af[t] = *(const half8*)&sA[(wm * 32 + t * 16 + (lane & 15)) * 40 + (lane >> 4) * 8];
#pragma unroll
    for (int t = 0; t < 4; ++t)
      bf[t] = *(const half8*)&sBT[(wn * 64 + t * 16 + (lane & 15)) * 40 + (lane >> 4) * 8];
#pragma unroll
    for (int tm = 0; tm < 2; ++tm)
#pragma unroll
      for (int tn = 0; tn < 4; ++tn)
        acc[tm][tn] = __builtin_amdgcn_mfma_f32_16x16x32_f16(af[tm], bf[tn], acc[tm][tn], 0, 0, 0);
    __syncthreads();
  }

  // ---- stats from registers ----
  float bsv[4];
#pragma unroll
  for (int tn = 0; tn < 4; ++tn) bsv[tn] = bias[wn * 64 + tn * 16 + (lane & 15)];
  {
    float sacc[4] = {0.f, 0.f, 0.f, 0.f}, qacc[4] = {0.f, 0.f, 0.f, 0.f};
#pragma unroll
    for (int tm = 0; tm < 2; ++tm) {
      int nbase = m0 + wm * 32 + tm * 16 + (lane >> 4) * 4;
#pragma unroll
      for (int r = 0; r < 4; ++r) {
        if (nbase + r < N_NODES) {
#pragma unroll
          for (int tn = 0; tn < 4; ++tn) {
            float v = acc[tm][tn][r] + bsv[tn];
            sacc[tn] += v; qacc[tn] += v * v;
          }
        }
      }
    }
#pragma unroll
    for (int tn = 0; tn < 4; ++tn) {
      int c = wn * 64 + tn * 16 + (lane & 15);
      atomicAdd(&ssum[c], sacc[tn]);
      atomicAdd(&ssq[c], qacc[tn]);
    }
  }

  // ---- chunked vectorized store (2 chunks x 32 rows) ----
  for (int c = 0; c < 2; ++c) {
    __syncthreads();
    if (wm == c) {
#pragma unroll
      for (int tm = 0; tm < 2; ++tm)
#pragma unroll
        for (int tn = 0; tn < 4; ++tn)
#pragma unroll
          for (int r = 0; r < 4; ++r)
            sOut[(tm * 16 + (lane >> 4) * 4 + r) * 132 + wn * 64 + tn * 16 + (lane & 15)] =
                acc[tm][tn][r] + bsv[tn];
    }
    __syncthreads();
    int row = tid >> 3;
    int cb = (tid & 7) * 16;
    int gn = m0 + c * 32 + row;
    if (gn < N_NODES) {
      const float* rp = &sOut[row * 132 + cb];
      half8 o0, o1;
#pragma unroll
      for (int q = 0; q < 8; ++q) o0[q] = (_Float16)rp[q];
#pragma unroll
      for (int q = 0; q < 8; ++q) o1[q] = (_Float16)rp[8 + q];
      *(half8*)&y2[(size_t)gn * 128 + cb] = o0;
      *(half8*)&y2[(size_t)gn * 128 + cb + 8] = o1;
    }
  }
  __syncthreads();
  if (tid < 128) {
    unsafeAtomicAdd(&gsum[tid], ssum[tid]);
    unsafeAtomicAdd(&gsq[tid], ssq[tid]);
  }
}

// ---------------- pooling with inlined final BN ----------------
__global__ void k_goff(const int* __restrict__ batch, int* __restrict__ goff) {
  int g = blockIdx.x * blockDim.x + threadIdx.x;
  if (g <= NG) {
    if (g == NG) { goff[g] = N_NODES; return; }
    int lo = 0, hi = N_NODES;
    while (lo < hi) { int mid = (lo + hi) >> 1; if (batch[mid] < g) lo = mid + 1; else hi = mid; }
    goff[g] = lo;
  }
}

__global__ __launch_bounds__(256) void k_poolseg(const _Float16* __restrict__ y2raw,
                                                 const float* __restrict__ gsum2,
                                                 const float* __restrict__ gsq2,
                                                 const float* __restrict__ bng,
                                                 const float* __restrict__ bnb,
                                                 const int* __restrict__ goff,
                                                 float* __restrict__ pooled) {
  __shared__ float sred[256];
  int g = blockIdx.x;
  int c = threadIdx.x & 127;
  int half = threadIdx.x >> 7;
  int n0 = goff[g], n1 = goff[g + 1];
  float s = 0.f;
  for (int n = n0 + half; n < n1; n += 2) s += (float)y2raw[(size_t)n * HD + c];
  sred[threadIdx.x] = s;
  __syncthreads();
  if (threadIdx.x < 128) {
    const float invN = 1.0f / (float)N_NODES;
    float m = gsum2[threadIdx.x] * invN;
    float v = fmaxf(gsq2[threadIdx.x] * invN - m * m, 0.0f);
    float scv = bng[threadIdx.x] * rsqrtf(v + BN_EPS);
    float shv = bnb[threadIdx.x] - m * scv;
    float tot = sred[threadIdx.x] + sred[threadIdx.x + 128];
    float cntf = fmaxf((float)(n1 - n0), 1.0f);
    pooled[g * HD + threadIdx.x] = scv * (tot / cntf) + shv;
  }
}

// ---------------- final GEMM ----------------
__global__ __launch_bounds__(128) void k_final(const float* __restrict__ pooled,
                                               const float* __restrict__ oW,
                                               const float* __restrict__ ob,
                                               float* __restrict__ out) {
  __shared__ float sP[HD];
  int g = blockIdx.x;
  int c = threadIdx.x;
  sP[c] = pooled[g * HD + c];
  __syncthreads();
  float acc = ob[c];
#pragma unroll 8
  for (int k = 0; k < HD; ++k) acc += sP[k] * oW[k * HD + c];
  out[g * HD + c] = acc;
}

extern "C" void kernel_launch(void* const* d_in, const int* in_sizes, int n_in,
                              void* d_out, int out_size, void* d_ws, size_t ws_size,
                              hipStream_t stream) {
  const int* x = (const int*)d_in[0];
  const int* ei = (const int*)d_in[1];
  const float* ea = (const float*)d_in[2];
  const int* batch = (const int*)d_in[3];
  const float* emb = (const float*)d_in[4];
  const float* eW = (const float*)d_in[5];
  const float* eb = (const float*)d_in[6];
  const float* epsA = (const float*)d_in[7];
  const float* W1 = (const float*)d_in[8];
  const float* b1 = (const float*)d_in[9];
  const float* g1 = (const float*)d_in[10];
  const float* be1 = (const float*)d_in[11];
  const float* W2 = (const float*)d_in[12];
  const float* b2 = (const float*)d_in[13];
  const float* bng = (const float*)d_in[14];
  const float* bnb = (const float*)d_in[15];
  const float* oW = (const float*)d_in[16];
  const float* ob = (const float*)d_in[17];
  float* out = (float*)d_out;

  // ----- workspace layout: ints first, then floats -----
  int* ip = (int*)d_ws;
  int* deg = ip;                              // 50,000
  int* incl = deg + 50000;                    // 50,000
  int* offs = incl + 50000;                   // 50,001
  int* cursor = offs + 50001;                 // 50,000
  int2* edata = (int2*)(cursor + 50000 + 1);  // 800,000 int2 (8B aligned)
  int* srcs = (int*)(edata + 800000);         // 800,000
  int* bsum = srcs + 800000;                  // 200
  int* goff = bsum + 200;                     // 513
  float* fp = (float*)(ip + 2600716);
  _Float16* h = (_Float16*)fp;                       // 6.4M halves (3.2M float slots)
  _Float16* zbuf = (_Float16*)(fp + 3200000);        // 6.4M halves
  _Float16* y1h = (_Float16*)(fp + 6400000);         // 12.8M halves (6.4M float slots)
  _Float16* ea_h = (_Float16*)(fp + 12800000);       // 12.8M halves = 6.4M float slots
  float* statsA = fp + 25600000;              // 5 * 768 arena (6.4M slack above ea_h — safe)
  float* pooled = statsA + 3840;              // 65,536
  _Float16* w1t = (_Float16*)(pooled + 65536);       // 163,840 halves
  _Float16* w2t = w1t + 163840;                      // 163,840 halves
  _Float16* eWh = w2t + 163840;                      // 10,240 halves

  const int edge_blocks = (N_EDGES + 255) / 256;
  const int node_blocks = (N_NODES + 255) / 256;

  k_embed<<<(N_NODES * 16 + 255) / 256, 256, 0, stream>>>(x, emb, h);

  // CSR build + permuted fp16 ea + weight conversion + stats arena zero (once per launch)
  hipMemsetAsync(deg, 0, 50000 * sizeof(int), stream);
  hipMemsetAsync(statsA, 0, 3840 * sizeof(float), stream);
  k_hist<<<edge_blocks, 256, 0, stream>>>(ei, deg);
  k_scan1<<<node_blocks, 256, 0, stream>>>(deg, incl, bsum);
  k_scan2<<<1, 256, 0, stream>>>(bsum, node_blocks);
  k_scan3<<<node_blocks, 256, 0, stream>>>(deg, incl, bsum, offs, cursor);
  k_scatter<<<edge_blocks, 256, 0, stream>>>(ei, cursor, edata);
  k_permea<<<edge_blocks, 256, 0, stream>>>(edata, ea, srcs, ea_h);
  k_goff<<<3, 256, 0, stream>>>(batch, goff);
  k_cvtw<<<(337920 + 255) / 256, 256, 0, stream>>>(W1, W2, eW, w1t, w2t, eWh);

  for (int l = 0; l < NLAYERS; ++l) {
    float* st = statsA + (size_t)l * 768;         // gsum1 | gsq1 (256+256)
    float* st2 = st + 512;                        // gsum2 | gsq2 (128+128)
    const float* pst2 = statsA + (size_t)(l - 1) * 768 + 512;  // prev layer gemm2 stats
    k_aggr<<<(N_NODES + 1) / 2, 256, 0, stream>>>(offs, srcs, ea_h,
                                                  eWh + (size_t)l * EINC * HD, eb + l * HD,
                                                  epsA, l, h,
                                                  (l > 0) ? pst2 : statsA, (l > 0) ? pst2 + 128 : statsA,
                                                  bng + (l > 0 ? (l - 1) : 0) * HD,
                                                  bnb + (l > 0 ? (l - 1) : 0) * HD,
                                                  (l > 0) ? 1 : 0, zbuf);
    k_gemm1m<<<dim3(391, 2), 256, 0, stream>>>(zbuf, w1t + (size_t)l * 32768,
                                               b1 + l * 256, y1h, st, st + 256);
    k_gemm2m<<<782, 256, 0, stream>>>(y1h, st, st + 256, g1 + l * 256, be1 + l * 256,
                                      w2t + (size_t)l * 32768, b2 + l * HD, h,
                                      st2, st2 + 128);
  }

  {
    const float* lst2 = statsA + (size_t)(NLAYERS - 1) * 768 + 512;
    k_poolseg<<<NG, 256, 0, stream>>>(h, lst2, lst2 + 128,
                                      bng + (NLAYERS - 1) * HD, bnb + (NLAYERS - 1) * HD,
                                      goff, pooled);
  }
  k_final<<<NG, 128, 0, stream>>>(pooled, oW, ob, out);
}